// Round 6
// baseline (210.508 us; speedup 1.0000x reference)
//
#include <hip/hip_runtime.h>
#include <hip/hip_bf16.h>

// Problem constants (from reference)
#define N_NODES 100000
#define FEAT    256
#define HID     128
#define REL     2
#define BATCH   20000
#define KNEI    10

typedef short  bf16x8 __attribute__((ext_vector_type(8)));
typedef _Float16 half8 __attribute__((ext_vector_type(8)));
typedef float  f32x4  __attribute__((ext_vector_type(4)));

// ---------------- fp16 helpers ----------------
__device__ __forceinline__ unsigned short f2h(float x) {
    union { _Float16 h; unsigned short u; } t; t.h = (_Float16)x; return t.u;
}
__device__ __forceinline__ ushort4 pack4h(float a, float b, float c, float d) {
    ushort4 p; p.x = f2h(a); p.y = f2h(b); p.z = f2h(c); p.w = f2h(d); return p;
}

// ---------------- bf16 helpers (fallback path) ----------------
__device__ __forceinline__ unsigned short f2bf(float x) {
    union { float f; unsigned u; } v; v.f = x;
    unsigned r = v.u + 0x7fffu + ((v.u >> 16) & 1u);
    return (unsigned short)(r >> 16);
}
__device__ __forceinline__ ushort4 pack4(float a, float b, float c, float d) {
    ushort4 p; p.x = f2bf(a); p.y = f2bf(b); p.z = f2bf(c); p.w = f2bf(d); return p;
}

// Swizzled B index for logical (k, n), NT n-tiles per kt row:
//   kt=k>>5, j=k&7, hi=(k>>3)&3, lane=hi*16+(n&15), nt=n>>4
//   dest = ((kt*NT+nt)*64 + lane)*8 + j
__device__ __forceinline__ size_t bswi(int k, int n, int NT) {
    int kt = k >> 5, j = k & 7, hi = (k >> 3) & 3;
    int lane = hi * 16 + (n & 15), nt = n >> 4;
    return ((size_t)(kt * NT + nt) * 64 + lane) * 8 + j;
}

// ===========================================================================
// NEW PATH (needs ~51.5 MB workspace)
//   prep_Bf16 : Wd (512x128) and Wstc (256x256) -> fp16 MFMA-swizzled
//   prep_P    : P[rel][node][128] = features[node] @ W_stc[rel]  (fp16 table)
//   fused2    : gather self (1KB) + P rows (256B) -> K=512 fp16 GEMM + ReLU
// ===========================================================================

// blocks 0..63: Bsw_det (NT=8); blocks 64..127: Bsw_stc (NT=16)
__global__ __launch_bounds__(256) void prep_Bf16(const float* __restrict__ W_stc,
                                                 const float* __restrict__ W_det,
                                                 unsigned short* __restrict__ Bsw_det,
                                                 unsigned short* __restrict__ Bsw_stc) {
    const int blk = blockIdx.x, tid = threadIdx.x;
    if (blk < 64) {
        #pragma unroll
        for (int i = 0; i < 4; ++i) {
            const int idx = blk * 1024 + i * 256 + tid;   // < 65536
            const int k = idx >> 7, n = idx & 127;
            Bsw_det[bswi(k, n, 8)] = f2h(W_det[idx]);
        }
    } else {
        #pragma unroll
        for (int i = 0; i < 4; ++i) {
            const int idx = (blk - 64) * 1024 + i * 256 + tid;  // < 65536
            const int f = idx >> 8, n = idx & 255;
            const int rel = n >> 7, h = n & 127;
            Bsw_stc[bswi(f, n, 16)] = f2h(W_stc[(size_t)(rel * FEAT + f) * HID + h]);
        }
    }
}

// One block per 16 nodes: stream 16KB of features -> fp16 LDS tile ->
// 8kt x 4nt MFMA per wave (N=256 = [rel0 h | rel1 h]) -> coalesced P stores.
#define APROW 264   // 256 + 8 pad (fp16 elems)
__global__ __launch_bounds__(256) void prep_P(const float* __restrict__ features,
                                              const unsigned short* __restrict__ Bsw_stc,
                                              unsigned short* __restrict__ P) {
    __shared__ __align__(16) unsigned short Ap[16 * APROW];   // 8448 B
    __shared__ __align__(16) unsigned short Cs[16 * 256];     // 8192 B
    const int blk = blockIdx.x, tid = threadIdx.x;
    const int w = tid >> 6, lane = tid & 63;
    const float4* F4 = (const float4*)features;

    #pragma unroll
    for (int s = 0; s < 4; ++s) {
        const int g = s * 256 + tid;            // 0..1023
        const int row = g >> 6, c4 = g & 63;
        float4 v = F4[(size_t)(blk * 16 + row) * 64 + c4];
        *(ushort4*)(Ap + row * APROW + c4 * 4) = pack4h(v.x, v.y, v.z, v.w);
    }
    __syncthreads();

    const int quad = lane >> 4, l16 = lane & 15;
    const unsigned short* a_base = Ap + l16 * APROW + quad * 8;
    f32x4 acc[4] = {{0,0,0,0},{0,0,0,0},{0,0,0,0},{0,0,0,0}};
    #pragma unroll
    for (int kt = 0; kt < 8; ++kt) {
        half8 a = *(const half8*)(a_base + kt * 32);
        #pragma unroll
        for (int t = 0; t < 4; ++t) {
            const int nt = w + t * 4;
            half8 b = *(const half8*)(Bsw_stc + ((size_t)(kt * 16 + nt) * 64 + lane) * 8);
            acc[t] = __builtin_amdgcn_mfma_f32_16x16x32_f16(a, b, acc[t], 0, 0, 0);
        }
    }
    #pragma unroll
    for (int t = 0; t < 4; ++t) {
        const int nt = w + t * 4;
        #pragma unroll
        for (int r = 0; r < 4; ++r)
            Cs[(quad * 4 + r) * 256 + nt * 16 + l16] = f2h(acc[t][r]);
    }
    __syncthreads();

    // BUG FIX (round 5): each thread owns a 16-half segment; previous code
    // copied only 8 halves (ushort4 = 4 shorts), leaving halves 8..15 of
    // every segment UNINITIALIZED -> absmax 0.836. Two uint4 = 16 halves.
    const int seg = tid >> 3, part = tid & 7;   // seg 0..31 = (row, rel)
    const int row = seg >> 1, rel = seg & 1;
    const unsigned short* src = Cs + row * 256 + rel * 128 + part * 16;
    unsigned short* dst = P + (size_t)rel * N_NODES * HID
                            + (size_t)(blk * 16 + row) * HID + part * 16;
    *(uint4*)(dst)     = *(const uint4*)(src);      // halves 0..7
    *(uint4*)(dst + 8) = *(const uint4*)(src + 8);  // halves 8..15
}

// fused2: A row = [self fp16 (256) | meanP0 (128) | meanP1 (128)], K=512.
#define AROW2 520   // 512 + 8 pad (fp16 elems)
__global__ __launch_bounds__(256, 6) void fused2(const int* __restrict__ nodes,
                                                 const int* __restrict__ neigh_idx,
                                                 const float* __restrict__ features,
                                                 const unsigned short* __restrict__ P,
                                                 const unsigned short* __restrict__ Bsw_det,
                                                 float* __restrict__ out) {
    __shared__ __align__(16) unsigned short As[16 * AROW2];  // 16640 B
    __shared__ int idxs[336];

    const int blk = blockIdx.x, tid = threadIdx.x;
    const int w = tid >> 6, lane = tid & 63;
    const int grp = lane >> 4, l16 = lane & 15;
    const float4* F4 = (const float4*)features;
    const float inv = 1.0f / (float)KNEI;

    // Phase 0: stage indices
    if (tid < 16)       idxs[tid] = nodes[blk * 16 + tid];
    else if (tid < 176) idxs[tid] = neigh_idx[blk * 160 + (tid - 16)];
    else                idxs[tid] = neigh_idx[BATCH * KNEI + blk * 160 + (tid - 176)];
    const int t2 = tid + 256;
    if (t2 < 336)       idxs[t2] = neigh_idx[BATCH * KNEI + blk * 160 + (t2 - 176)];
    __syncthreads();

    // Phase 1: self gather (1KB f32) + P-row gather (256B fp16, 4 rows/load)
    #pragma unroll
    for (int e = 0; e < 4; ++e) {
        const int m = w * 4 + e;
        float4 sf = F4[(size_t)idxs[m] * 64 + lane];
        *(ushort4*)(As + m * AROW2 + lane * 4) = pack4h(sf.x, sf.y, sf.z, sf.w);

        #pragma unroll
        for (int r = 0; r < 2; ++r) {
            const int* ir = &idxs[16 + r * 160 + m * KNEI];
            const unsigned short* Pr = P + (size_t)r * N_NODES * HID;
            float acc[8] = {0.f,0.f,0.f,0.f,0.f,0.f,0.f,0.f};
            #pragma unroll
            for (int L = 0; L < 3; ++L) {
                const int kk = L * 4 + grp;
                const int nd = ir[kk < KNEI ? kk : KNEI - 1];
                uint4 raw = *(const uint4*)(Pr + (size_t)nd * HID + l16 * 8);
                float v[8];
                union { unsigned u; _Float16 h[2]; } t;
                t.u = raw.x; v[0] = (float)t.h[0]; v[1] = (float)t.h[1];
                t.u = raw.y; v[2] = (float)t.h[0]; v[3] = (float)t.h[1];
                t.u = raw.z; v[4] = (float)t.h[0]; v[5] = (float)t.h[1];
                t.u = raw.w; v[6] = (float)t.h[0]; v[7] = (float)t.h[1];
                if (L < 2 || lane < 32) {          // mask duplicate clamp rows
                    #pragma unroll
                    for (int j = 0; j < 8; ++j) acc[j] += v[j];
                }
            }
            #pragma unroll
            for (int j = 0; j < 8; ++j) acc[j] += __shfl_xor(acc[j], 16);
            #pragma unroll
            for (int j = 0; j < 8; ++j) acc[j] += __shfl_xor(acc[j], 32);
            if (lane < 16) {
                unsigned short* d = As + m * AROW2 + 256 + r * 128 + lane * 8;
                *(ushort4*)(d)     = pack4h(acc[0]*inv, acc[1]*inv, acc[2]*inv, acc[3]*inv);
                *(ushort4*)(d + 4) = pack4h(acc[4]*inv, acc[5]*inv, acc[6]*inv, acc[7]*inv);
            }
        }
    }
    __syncthreads();

    // Phase 2: K=512 fp16 GEMM + ReLU
    const unsigned short* a_base = As + l16 * AROW2 + grp * 8;
    f32x4 acc0 = (f32x4){0.f,0.f,0.f,0.f};
    f32x4 acc1 = (f32x4){0.f,0.f,0.f,0.f};
    const int nt0 = w, nt1 = w + 4;
    #pragma unroll
    for (int kt = 0; kt < 16; ++kt) {
        half8 a = *(const half8*)(a_base + kt * 32);
        const unsigned short* bk = Bsw_det + ((size_t)(kt * 8) * 64 + lane) * 8;
        half8 b0 = *(const half8*)(bk + (size_t)nt0 * 512);
        half8 b1 = *(const half8*)(bk + (size_t)nt1 * 512);
        acc0 = __builtin_amdgcn_mfma_f32_16x16x32_f16(a, b0, acc0, 0, 0, 0);
        acc1 = __builtin_amdgcn_mfma_f32_16x16x32_f16(a, b1, acc1, 0, 0, 0);
    }
    float* orow = out + (size_t)(blk * 16) * HID;
    #pragma unroll
    for (int r = 0; r < 4; ++r) {
        const int row = grp * 4 + r;
        float v0 = acc0[r], v1 = acc1[r];
        orow[(size_t)row * HID + nt0 * 16 + l16] = v0 > 0.f ? v0 : 0.f;
        orow[(size_t)row * HID + nt1 * 16 + l16] = v1 > 0.f ? v1 : 0.f;
    }
}

// ===========================================================================
// FALLBACK PATH (round-4 verbatim, needs only 192 KB workspace)
// ===========================================================================
#define APAD    8
#define AROW    (768 + APAD)

__device__ __forceinline__ size_t bsw_index(int k, int n) {
    int kt = k >> 5, j = k & 7, hi = (k >> 3) & 3;
    int lane = hi * 16 + (n & 15), nt = n >> 4;
    return ((size_t)(kt * 8 + nt) * 64 + lane) * 8 + j;
}

__global__ __launch_bounds__(256) void prep_B_old(const float* __restrict__ W_stc,
                                                  const float* __restrict__ W_det,
                                                  unsigned short* __restrict__ Bsw) {
    const int blk = blockIdx.x;
    const int tid = threadIdx.x;
    if (blk < 256) {
        const int rel = blk >> 7;
        const int f   = (blk & 127) * 2 + (tid >> 7);
        const int n   = tid & 127;
        const float* ws = W_stc + (size_t)(rel * FEAT + f) * HID;
        const float* wd = W_det + (size_t)(256 + rel * HID) * HID + n;
        float acc = 0.f;
        #pragma unroll
        for (int j = 0; j < HID; ++j) acc += ws[j] * wd[(size_t)j * HID];
        Bsw[bsw_index(256 + rel * 256 + f, n)] = f2bf(acc);
    } else {
        const int base = (blk - 256) * 2048;
        #pragma unroll
        for (int i = 0; i < 8; ++i) {
            const int idx = base + i * 256 + tid;
            const int k = idx >> 7, n = idx & 127;
            Bsw[bsw_index(k, n)] = f2bf(W_det[idx]);
        }
    }
}

__global__ __launch_bounds__(256, 4) void fused_old(const int* __restrict__ nodes,
                                                    const int* __restrict__ neigh_idx,
                                                    const float* __restrict__ features,
                                                    const unsigned short* __restrict__ Bsw,
                                                    float* __restrict__ out) {
    __shared__ unsigned short As[16 * AROW];
    __shared__ int idxs[336];

    const int blk  = blockIdx.x;
    const int tid  = threadIdx.x;
    const int w    = tid >> 6;
    const int lane = tid & 63;
    const float inv = 1.0f / (float)KNEI;

    if (tid < 16)       idxs[tid] = nodes[blk * 16 + tid];
    else if (tid < 176) idxs[tid] = neigh_idx[blk * 160 + (tid - 16)];
    else                idxs[tid] = neigh_idx[BATCH * KNEI + blk * 160 + (tid - 176)];
    const int t2 = tid + 256;
    if (t2 < 336)       idxs[t2] = neigh_idx[BATCH * KNEI + blk * 160 + (t2 - 176)];
    __syncthreads();

    const unsigned lnoff = (unsigned)lane << 4;
    #pragma unroll
    for (int e = 0; e < 4; ++e) {
        const int m = w * 4 + e;
        int ia[11], ib[10];
        ia[0] = idxs[m];
        #pragma unroll
        for (int k = 0; k < KNEI; ++k) ia[1 + k] = idxs[16 + m * KNEI + k];
        #pragma unroll
        for (int k = 0; k < KNEI; ++k) ib[k]     = idxs[176 + m * KNEI + k];

        f32x4 ta[11];
        #pragma unroll
        for (int k = 0; k < 11; ++k) {
            const unsigned voff = ((unsigned)ia[k] << 10) + lnoff;
            asm volatile("global_load_dwordx4 %0, %1, %2"
                         : "=v"(ta[k]) : "v"(voff), "s"(features));
        }
        f32x4 tb[10];
        #pragma unroll
        for (int k = 0; k < KNEI; ++k) {
            const unsigned voff = ((unsigned)ib[k] << 10) + lnoff;
            asm volatile("global_load_dwordx4 %0, %1, %2"
                         : "=v"(tb[k]) : "v"(voff), "s"(features));
        }

        asm volatile("s_waitcnt vmcnt(10)" ::: "memory");
        __builtin_amdgcn_sched_barrier(0);

        f32x4 s0 = ta[1];
        #pragma unroll
        for (int k = 2; k < 11; ++k) s0 += ta[k];

        ushort4* row = (ushort4*)(As + m * AROW);
        row[lane]      = pack4(ta[0][0], ta[0][1], ta[0][2], ta[0][3]);
        row[64 + lane] = pack4(s0[0] * inv, s0[1] * inv, s0[2] * inv, s0[3] * inv);

        asm volatile("s_waitcnt vmcnt(0)" ::: "memory");
        __builtin_amdgcn_sched_barrier(0);

        f32x4 s1 = tb[0];
        #pragma unroll
        for (int k = 1; k < KNEI; ++k) s1 += tb[k];
        row[128 + lane] = pack4(s1[0] * inv, s1[1] * inv, s1[2] * inv, s1[3] * inv);
    }
    __syncthreads();

    const int quad = lane >> 4;
    const int l16  = lane & 15;
    const unsigned short* a_base = As + l16 * AROW + quad * 8;

    f32x4 acc0 = (f32x4){0.f, 0.f, 0.f, 0.f};
    f32x4 acc1 = (f32x4){0.f, 0.f, 0.f, 0.f};
    const int nt0 = w, nt1 = w + 4;

    #pragma unroll
    for (int kt = 0; kt < 24; ++kt) {
        bf16x8 a = *(const bf16x8*)(a_base + kt * 32);
        const unsigned short* bk = Bsw + ((size_t)(kt * 8) * 64 + lane) * 8;
        bf16x8 b0 = *(const bf16x8*)(bk + (size_t)nt0 * 64 * 8);
        bf16x8 b1 = *(const bf16x8*)(bk + (size_t)nt1 * 64 * 8);
        acc0 = __builtin_amdgcn_mfma_f32_16x16x32_bf16(a, b0, acc0, 0, 0, 0);
        acc1 = __builtin_amdgcn_mfma_f32_16x16x32_bf16(a, b1, acc1, 0, 0, 0);
    }

    float* orow = out + (size_t)(blk * 16) * HID;
    #pragma unroll
    for (int r = 0; r < 4; ++r) {
        const int row = quad * 4 + r;
        float v0 = acc0[r];
        float v1 = acc1[r];
        orow[(size_t)row * HID + nt0 * 16 + l16] = v0 > 0.f ? v0 : 0.f;
        orow[(size_t)row * HID + nt1 * 16 + l16] = v1 > 0.f ? v1 : 0.f;
    }
}

// ===========================================================================
extern "C" void kernel_launch(void* const* d_in, const int* in_sizes, int n_in,
                              void* d_out, int out_size, void* d_ws, size_t ws_size,
                              hipStream_t stream) {
    const int*   nodes     = (const int*)d_in[0];
    const int*   neigh_idx = (const int*)d_in[1];
    const float* features  = (const float*)d_in[2];
    const float* W_stc     = (const float*)d_in[3];
    const float* W_det     = (const float*)d_in[4];
    float* out = (float*)d_out;

    const size_t P_BYTES   = (size_t)REL * N_NODES * HID * 2;   // 51,200,000
    const size_t BD_BYTES  = 512 * 128 * 2;                     // 131,072
    const size_t BS_BYTES  = 256 * 256 * 2;                     // 131,072
    const size_t WS_NEEDED = P_BYTES + BD_BYTES + BS_BYTES;

    if (ws_size >= WS_NEEDED) {
        unsigned short* P       = (unsigned short*)d_ws;
        unsigned short* Bsw_det = (unsigned short*)((char*)d_ws + P_BYTES);
        unsigned short* Bsw_stc = (unsigned short*)((char*)d_ws + P_BYTES + BD_BYTES);
        prep_Bf16<<<128, 256, 0, stream>>>(W_stc, W_det, Bsw_det, Bsw_stc);
        prep_P<<<N_NODES / 16, 256, 0, stream>>>(features, Bsw_stc, P);
        fused2<<<BATCH / 16, 256, 0, stream>>>(nodes, neigh_idx, features, P, Bsw_det, out);
    } else {
        unsigned short* Bsw = (unsigned short*)d_ws;            // 192 KB
        prep_B_old<<<272, 256, 0, stream>>>(W_stc, W_det, Bsw);
        fused_old<<<BATCH / 16, 256, 0, stream>>>(nodes, neigh_idx, features, Bsw, out);
    }
}